// Round 6
// baseline (1574.079 us; speedup 1.0000x reference)
//
#include <hip/hip_runtime.h>

#define NW 4096
#define SEQ 33
#define CC 256
#define NTOK 131072
#define NKC 27

typedef unsigned short u16;
typedef __attribute__((ext_vector_type(8))) short s16x8;
typedef __attribute__((ext_vector_type(4))) short s16x4;
typedef __attribute__((ext_vector_type(4))) float f32x4;

#define MFMA16(a,b,c) __builtin_amdgcn_mfma_f32_16x16x32_bf16((a),(b),(c),0,0,0)

__device__ __forceinline__ float bu2f(u16 u){ return __uint_as_float(((unsigned int)u)<<16); }
__device__ __forceinline__ u16 f2bu(float f){
  unsigned int u = __float_as_uint(f);
  return (u16)((u + 0x7FFFu + ((u>>16)&1u)) >> 16);
}

// ---- f32 -> bf16 convert (float4 vectorized) ----
__global__ void k_cvt(const float* __restrict__ in, u16* __restrict__ out, int n4){
  int stride = gridDim.x * blockDim.x;
  for (int i = blockIdx.x*blockDim.x + threadIdx.x; i < n4; i += stride){
    float4 v = ((const float4*)in)[i];
    s16x4 o;
    o[0] = (short)f2bu(v.x); o[1] = (short)f2bu(v.y);
    o[2] = (short)f2bu(v.z); o[3] = (short)f2bu(v.w);
    ((s16x4*)out)[i] = o;
  }
}

// ---- transpose f32 (R x C) -> bf16 (C x R) ----
__global__ void k_tr(const float* __restrict__ in, u16* __restrict__ out, int R, int C){
  int stride = gridDim.x * blockDim.x;
  int total = R*C;
  for (int i = blockIdx.x*blockDim.x + threadIdx.x; i < total; i += stride){
    int r = i / C, c = i - r*C;
    out[c*R + r] = f2bu(in[i]);
  }
}

// ---- relay rows (s=0) into x buffer ----
__global__ void k_relay(const float* __restrict__ rt, u16* __restrict__ xg){
  int stride = gridDim.x * blockDim.x;
  for (int i = blockIdx.x*blockDim.x + threadIdx.x; i < NW*CC; i += stride){
    int w = i >> 8, c = i & 255;
    xg[(w*SEQ)*CC + c] = f2bu(rt[i]);
  }
}

// ---- CPE gather + BN + residual -> x rows s=1..32 (16B/lane gathers) ----
__global__ void k_cpe(const float* __restrict__ data, const u16* __restrict__ datab,
                      const int* __restrict__ neigh, const float* __restrict__ cpw,
                      const float* __restrict__ bng, const float* __restrict__ bnb,
                      const float* __restrict__ bnm, const float* __restrict__ bnv,
                      u16* __restrict__ xg){
  int n = blockIdx.x*8 + (threadIdx.x >> 5);   // 8 tokens per 256-thr block
  int l = threadIdx.x & 31;
  int c0 = l*8;
  float a[8];
  #pragma unroll
  for (int j = 0; j < 8; ++j) a[j] = 0.f;
  const int* nr = neigh + n*NKC;
  for (int k = 0; k < NKC; ++k){
    int idx = nr[k];
    s16x8 d = *(const s16x8*)(datab + idx*CC + c0);
    float4 w0 = *(const float4*)(cpw + k*CC + c0);
    float4 w1 = *(const float4*)(cpw + k*CC + c0 + 4);
    a[0] += bu2f((u16)d[0])*w0.x; a[1] += bu2f((u16)d[1])*w0.y;
    a[2] += bu2f((u16)d[2])*w0.z; a[3] += bu2f((u16)d[3])*w0.w;
    a[4] += bu2f((u16)d[4])*w1.x; a[5] += bu2f((u16)d[5])*w1.y;
    a[6] += bu2f((u16)d[6])*w1.z; a[7] += bu2f((u16)d[7])*w1.w;
  }
  s16x8 o;
  #pragma unroll
  for (int half = 0; half < 2; ++half){
    float4 dv = *(const float4*)(data + n*CC + c0 + half*4);
    float4 g  = *(const float4*)(bng + c0 + half*4);
    float4 b  = *(const float4*)(bnb + c0 + half*4);
    float4 m  = *(const float4*)(bnm + c0 + half*4);
    float4 vv = *(const float4*)(bnv + c0 + half*4);
    float x0 = dv.x + (a[half*4+0] - m.x)*rsqrtf(vv.x + 1e-5f)*g.x + b.x;
    float x1 = dv.y + (a[half*4+1] - m.y)*rsqrtf(vv.y + 1e-5f)*g.y + b.y;
    float x2 = dv.z + (a[half*4+2] - m.z)*rsqrtf(vv.z + 1e-5f)*g.z + b.z;
    float x3 = dv.w + (a[half*4+3] - m.w)*rsqrtf(vv.w + 1e-5f)*g.w + b.w;
    o[half*4+0] = (short)f2bu(x0); o[half*4+1] = (short)f2bu(x1);
    o[half*4+2] = (short)f2bu(x2); o[half*4+3] = (short)f2bu(x3);
  }
  int w = n >> 5, s = (n & 31) + 1;
  *(s16x8*)(xg + (w*SEQ + s)*CC + c0) = o;
}

// ---- fused per-window transformer block, 16 waves / window ----
// Aliasing discipline (all padded garbage is FINITE by construction):
//  A: hs (LN out; rows 33-47 zero from init, garbage-finite after P overwrite
//     — FFN only needs finite) ∪ P[8][33][72] (cols 33-47 exact zeros from
//     masked exp; cols 48-63 finite garbage but VT rows 48-63 are zero)
//  B: Q (dead after scores) ∪ och (written by PV)
//  C2: K (dead after scores) ∪ mch (FFN mid chunk)
//  VT[256][72]: cols(t) 0-47 written by qkv; 48-63 stay zero from init.
struct SharedW {
  u16 xs[33][264];                                   // 17,424 B residual
  union { u16 hs[48][264]; u16 P[8][33][72]; } A;    // 38,016 B
  union { u16 Q[48][264];  u16 och[48][264]; } B;    // 25,344 B
  union { u16 K[48][264];  u16 mch[48][264]; } C2;   // 25,344 B
  u16 VT[256][72];                                   // 36,864 B
};                                                   // 142,992 B total
static_assert(sizeof(SharedW) <= 160*1024, "LDS budget (1 block/CU)");

__global__ __launch_bounds__(1024,4) void k_window(
    const u16* __restrict__ xg,
    const u16* __restrict__ qkvT, const u16* __restrict__ projT,
    const u16* __restrict__ fc1T, const u16* __restrict__ fc2T,
    const float* __restrict__ n1g, const float* __restrict__ n1b,
    const float* __restrict__ qkvb, const float* __restrict__ projb,
    const float* __restrict__ n2g, const float* __restrict__ n2b,
    const float* __restrict__ fc1b, const float* __restrict__ fc2b,
    float* __restrict__ out)
{
  __shared__ __align__(16) SharedW L;
  const int tid  = threadIdx.x;
  const int lane = tid & 63;
  const int wid  = tid >> 6;          // 0..15
  const int l15  = lane & 15;
  const int lg8  = (lane >> 4) * 8;
  const int lg4  = (lane >> 4) * 4;
  const int w    = blockIdx.x;
  const f32x4 fzero = {0.f,0.f,0.f,0.f};

  // zero everything except xs (xs fully overwritten by the load below)
  {
    f32x4* p = (f32x4*)((char*)&L + sizeof(L.xs));
    const int n16 = (int)((sizeof(SharedW) - sizeof(L.xs))/16);
    for (int i = tid; i < n16; i += 1024) p[i] = fzero;
  }
  // load x window (33 rows x 256 bf16)
  for (int ci = tid; ci < SEQ*32; ci += 1024){
    int r = ci >> 5, cp = (ci & 31) << 3;
    *(s16x8*)&L.xs[r][cp] = *(const s16x8*)(xg + (w*SEQ + r)*CC + cp);
  }
  __syncthreads();

  auto LN = [&](const float* gg, const float* bb){
    for (int r = wid; r < SEQ; r += 16){
      int c0 = lane*4;
      s16x4 xv = *(const s16x4*)&L.xs[r][c0];
      float v0 = bu2f((u16)xv[0]), v1 = bu2f((u16)xv[1]);
      float v2 = bu2f((u16)xv[2]), v3 = bu2f((u16)xv[3]);
      float s  = v0+v1+v2+v3;
      float s2 = v0*v0+v1*v1+v2*v2+v3*v3;
      #pragma unroll
      for (int msk = 1; msk < 64; msk <<= 1){
        s  += __shfl_xor(s, msk);
        s2 += __shfl_xor(s2, msk);
      }
      float mu = s * (1.f/256.f);
      float var = s2 * (1.f/256.f) - mu*mu;
      float rs = rsqrtf(var + 1e-5f);
      float4 gv = *(const float4*)(gg + c0);
      float4 bv = *(const float4*)(bb + c0);
      s16x4 o;
      o[0] = (short)f2bu((v0-mu)*rs*gv.x + bv.x);
      o[1] = (short)f2bu((v1-mu)*rs*gv.y + bv.y);
      o[2] = (short)f2bu((v2-mu)*rs*gv.z + bv.z);
      o[3] = (short)f2bu((v3-mu)*rs*gv.w + bv.w);
      *(s16x4*)&L.A.hs[r][c0] = o;
    }
  };
  LN(n1g, n1b);
  __syncthreads();

  // ===== QKV: 48x256 @ 256x768, 3 n-tiles per wave =====
  {
    #pragma unroll
    for (int i = 0; i < 3; ++i){
      int n = wid*3 + i;                 // n-tile 0..47
      int sel = n >> 4;                  // 0=q 1=k 2=v
      int cn  = (n & 15)*16 + l15;       // col within q/k/v
      int ncol = n*16 + l15;             // col within 768
      const u16* wrow = qkvT + ncol*CC + lg8;
      s16x8 bf[8];
      #pragma unroll
      for (int kk = 0; kk < 8; ++kk) bf[kk] = *(const s16x8*)(wrow + kk*32);
      float bias = qkvb[ncol];
      f32x4 acc[3] = {fzero, fzero, fzero};
      #pragma unroll
      for (int kk = 0; kk < 8; ++kk)
        #pragma unroll
        for (int m = 0; m < 3; ++m){
          s16x8 a = *(const s16x8*)&L.A.hs[m*16 + l15][kk*32 + lg8];
          acc[m] = MFMA16(a, bf[kk], acc[m]);
        }
      #pragma unroll
      for (int m = 0; m < 3; ++m)
        #pragma unroll
        for (int jj = 0; jj < 4; ++jj){
          int row = m*16 + lg4 + jj;
          float val = acc[m][jj] + bias;
          if (sel == 0)      L.B.Q[row][cn]  = f2bu(val*0.17677669529663687f); // fold attn scale
          else if (sel == 1) L.C2.K[row][cn] = f2bu(val);
          else               L.VT[cn][row]   = f2bu(val);
        }
    }
  }
  __syncthreads();

  // ===== scores + softmax: 2 waves per head (half0: m={0,2}, half1: m={1}) =====
  {
    const int h = wid & 7;
    const int half = wid >> 3;
    s16x8 bk[3];
    #pragma unroll
    for (int n = 0; n < 3; ++n) bk[n] = *(const s16x8*)&L.C2.K[n*16 + l15][h*32 + lg8];
    const int nm = half ? 1 : 2;
    for (int mi = 0; mi < nm; ++mi){
      int m = half ? 1 : (mi ? 2 : 0);
      s16x8 aq = *(const s16x8*)&L.B.Q[m*16 + l15][h*32 + lg8];
      f32x4 sc0 = MFMA16(aq, bk[0], fzero);
      f32x4 sc1 = MFMA16(aq, bk[1], fzero);
      f32x4 sc2 = MFMA16(aq, bk[2], fzero);
      #pragma unroll
      for (int jj = 0; jj < 4; ++jj){
        float a0 = sc0[jj];
        float a1 = sc1[jj];
        float a2 = (l15 == 0) ? sc2[jj] : -1e30f;   // only col 32 valid in tile n=2
        float mx = fmaxf(fmaxf(a0, a1), a2);
        #pragma unroll
        for (int msk = 1; msk < 16; msk <<= 1) mx = fmaxf(mx, __shfl_xor(mx, msk));
        float e0 = __expf(a0 - mx), e1 = __expf(a1 - mx), e2 = __expf(a2 - mx);
        float sm = e0 + e1 + e2;
        #pragma unroll
        for (int msk = 1; msk < 16; msk <<= 1) sm += __shfl_xor(sm, msk);
        float inv = 1.f / sm;
        int row = m*16 + lg4 + jj;
        if (row < SEQ){
          L.A.P[h][row][l15]      = f2bu(e0*inv);
          L.A.P[h][row][16 + l15] = f2bu(e1*inv);
          L.A.P[h][row][32 + l15] = f2bu(e2*inv);   // l15>0 writes exact zeros (cols 33-47)
        }
      }
    }
  }
  __syncthreads();   // Q dead; och (alias of Q) may now be written

  // ===== PV: 2 waves per head (n-tile = half), write och =====
  {
    const int h = wid & 7;
    const int half = wid >> 3;
    s16x8 pa0[3], pa1[3];
    #pragma unroll
    for (int m = 0; m < 3; ++m){
      int row = m*16 + l15; if (row > 32) row = 32;   // clamped: garbage rows are finite dups
      pa0[m] = *(const s16x8*)&L.A.P[h][row][lg8];
      pa1[m] = *(const s16x8*)&L.A.P[h][row][32 + lg8];
    }
    s16x8 bv0 = *(const s16x8*)&L.VT[h*32 + half*16 + l15][lg8];
    s16x8 bv1 = *(const s16x8*)&L.VT[h*32 + half*16 + l15][32 + lg8];
    int col = h*32 + half*16 + l15;
    #pragma unroll
    for (int m = 0; m < 3; ++m){
      f32x4 acc = MFMA16(pa0[m], bv0, fzero);
      acc = MFMA16(pa1[m], bv1, acc);
      #pragma unroll
      for (int jj = 0; jj < 4; ++jj)
        L.B.och[m*16 + lg4 + jj][col] = f2bu(acc[jj]);
    }
  }
  __syncthreads();

  // ===== proj (K=256 full, n-tile = wid) + residual into xs =====
  {
    int ncol = wid*16 + l15;
    const u16* wrow = projT + ncol*CC + lg8;
    s16x8 bf[8];
    #pragma unroll
    for (int kk = 0; kk < 8; ++kk) bf[kk] = *(const s16x8*)(wrow + kk*32);
    f32x4 acc[3] = {fzero, fzero, fzero};
    #pragma unroll
    for (int kk = 0; kk < 8; ++kk)
      #pragma unroll
      for (int m = 0; m < 3; ++m){
        s16x8 a = *(const s16x8*)&L.B.och[m*16 + l15][kk*32 + lg8];
        acc[m] = MFMA16(a, bf[kk], acc[m]);
      }
    float pb = projb[ncol];
    #pragma unroll
    for (int m = 0; m < 3; ++m)
      #pragma unroll
      for (int jj = 0; jj < 4; ++jj){
        int row = m*16 + lg4 + jj;
        if (row < SEQ){
          float x = bu2f(L.xs[row][ncol]) + acc[m][jj] + pb;
          L.xs[row][ncol] = f2bu(x);
        }
      }
  }
  __syncthreads();

  LN(n2g, n2b);
  __syncthreads();

  // ===== FFN: 4 chunks of 256 mid-cols; fc2 accumulated in registers =====
  f32x4 accF[3] = {fzero, fzero, fzero};

  for (int nc = 0; nc < 4; ++nc){
    // fc1: n-tile = wid within chunk, + gelu -> mch
    {
      int nl = wid*16 + l15;                // 0..255 within chunk
      int ncol = nc*256 + nl;
      const u16* wrow = fc1T + ncol*CC + lg8;
      s16x8 bf[8];
      #pragma unroll
      for (int kk = 0; kk < 8; ++kk) bf[kk] = *(const s16x8*)(wrow + kk*32);
      float bias = fc1b[ncol];
      f32x4 acc[3] = {fzero, fzero, fzero};
      #pragma unroll
      for (int kk = 0; kk < 8; ++kk)
        #pragma unroll
        for (int m = 0; m < 3; ++m){
          s16x8 a = *(const s16x8*)&L.A.hs[m*16 + l15][kk*32 + lg8];
          acc[m] = MFMA16(a, bf[kk], acc[m]);
        }
      #pragma unroll
      for (int m = 0; m < 3; ++m)
        #pragma unroll
        for (int jj = 0; jj < 4; ++jj){
          int row = m*16 + lg4 + jj;
          float xv = acc[m][jj] + bias;
          // gelu(tanh) == x * sigmoid(2z), z = 0.79788456*(x + 0.044715 x^3)
          float z2 = 1.5957691216057308f*(xv + 0.044715f*xv*xv*xv);
          float gl = xv / (1.f + __expf(-z2));
          L.C2.mch[row][nl] = f2bu(gl);
        }
    }
    __syncthreads();
    // fc2 partial accumulate (K-chunk = 256), n-tile = wid
    {
      const u16* wrow = fc2T + (wid*16 + l15)*1024 + nc*256 + lg8;
      s16x8 bf[8];
      #pragma unroll
      for (int kk = 0; kk < 8; ++kk) bf[kk] = *(const s16x8*)(wrow + kk*32);
      #pragma unroll
      for (int kk = 0; kk < 8; ++kk)
        #pragma unroll
        for (int m = 0; m < 3; ++m){
          s16x8 a = *(const s16x8*)&L.C2.mch[m*16 + l15][kk*32 + lg8];
          accF[m] = MFMA16(a, bf[kk], accF[m]);
        }
    }
    __syncthreads();
  }

  // ===== final: x + ffn, write data_out / rt =====
  {
    int col = wid*16 + l15;
    float fb = fc2b[col];
    #pragma unroll
    for (int m = 0; m < 3; ++m)
      #pragma unroll
      for (int jj = 0; jj < 4; ++jj){
        int row = m*16 + lg4 + jj;
        if (row < SEQ){
          float x = bu2f(L.xs[row][col]) + accF[m][jj] + fb;
          if (row == 0) out[NTOK*CC + w*CC + col] = x;          // relay tokens
          else          out[(w*32 + row - 1)*CC + col] = x;      // data_out
        }
      }
  }
}

extern "C" void kernel_launch(void* const* d_in, const int* in_sizes, int n_in,
                              void* d_out, int out_size, void* d_ws, size_t ws_size,
                              hipStream_t stream){
  const float* data  = (const float*)d_in[0];
  const float* relay = (const float*)d_in[1];
  const int*   neigh = (const int*)d_in[2];
  const float* cpw   = (const float*)d_in[3];
  const float* bng   = (const float*)d_in[4];
  const float* bnb   = (const float*)d_in[5];
  const float* bnm   = (const float*)d_in[6];
  const float* bnv   = (const float*)d_in[7];
  const float* n1g   = (const float*)d_in[8];
  const float* n1b   = (const float*)d_in[9];
  const float* qkvw  = (const float*)d_in[10];
  const float* qkvb  = (const float*)d_in[11];
  const float* projw = (const float*)d_in[12];
  const float* projb = (const float*)d_in[13];
  const float* n2g   = (const float*)d_in[14];
  const float* n2b   = (const float*)d_in[15];
  const float* fc1w  = (const float*)d_in[16];
  const float* fc1b  = (const float*)d_in[17];
  const float* fc2w  = (const float*)d_in[18];
  const float* fc2b  = (const float*)d_in[19];

  char* ws = (char*)d_ws;
  u16* datab = (u16*)ws;                 // 131072*256*2      = 67,108,864 B
  u16* xg    = (u16*)(ws + 67108864);    // 135168*256*2      = 69,206,016 B
  u16* qkvT  = (u16*)(ws + 136314880);   // 768*256*2         =    393,216 B
  u16* projT = (u16*)(ws + 136708096);   // 256*256*2         =    131,072 B
  u16* fc1T  = (u16*)(ws + 136839168);   // 1024*256*2        =    524,288 B
  u16* fc2T  = (u16*)(ws + 137363456);   // 256*1024*2        =    524,288 B

  k_cvt<<<4096, 256, 0, stream>>>(data, datab, NTOK*CC/4);
  k_tr<<<256, 256, 0, stream>>>(qkvw, qkvT, 256, 768);
  k_tr<<<256, 256, 0, stream>>>(projw, projT, 256, 256);
  k_tr<<<256, 256, 0, stream>>>(fc1w, fc1T, 256, 1024);
  k_tr<<<256, 256, 0, stream>>>(fc2w, fc2T, 1024, 256);
  k_relay<<<1024, 256, 0, stream>>>(relay, xg);
  k_cpe<<<NTOK/8, 256, 0, stream>>>(data, datab, neigh, cpw, bng, bnb, bnm, bnv, xg);
  k_window<<<NW, 1024, 0, stream>>>(xg, qkvT, projT, fc1T, fc2T,
                                    n1g, n1b, qkvb, projb, n2g, n2b, fc1b, fc2b,
                                    (float*)d_out);
}

// Round 7
// 1569.474 us; speedup vs baseline: 1.0029x; 1.0029x over previous
//
#include <hip/hip_runtime.h>

#define NW 4096
#define SEQ 33
#define CC 256
#define NTOK 131072
#define NKC 27

typedef unsigned short u16;
typedef __attribute__((ext_vector_type(8))) short s16x8;
typedef __attribute__((ext_vector_type(4))) short s16x4;
typedef __attribute__((ext_vector_type(4))) float f32x4;

#define MFMA16(a,b,c) __builtin_amdgcn_mfma_f32_16x16x32_bf16((a),(b),(c),0,0,0)

__device__ __forceinline__ float bu2f(u16 u){ return __uint_as_float(((unsigned int)u)<<16); }
__device__ __forceinline__ u16 f2bu(float f){
  unsigned int u = __float_as_uint(f);
  return (u16)((u + 0x7FFFu + ((u>>16)&1u)) >> 16);
}

// ---- f32 -> bf16 convert (float4 vectorized) ----
__global__ void k_cvt(const float* __restrict__ in, u16* __restrict__ out, int n4){
  int stride = gridDim.x * blockDim.x;
  for (int i = blockIdx.x*blockDim.x + threadIdx.x; i < n4; i += stride){
    float4 v = ((const float4*)in)[i];
    s16x4 o;
    o[0] = (short)f2bu(v.x); o[1] = (short)f2bu(v.y);
    o[2] = (short)f2bu(v.z); o[3] = (short)f2bu(v.w);
    ((s16x4*)out)[i] = o;
  }
}

// ---- transpose f32 (R x C) -> bf16 (C x R) ----
__global__ void k_tr(const float* __restrict__ in, u16* __restrict__ out, int R, int C){
  int stride = gridDim.x * blockDim.x;
  int total = R*C;
  for (int i = blockIdx.x*blockDim.x + threadIdx.x; i < total; i += stride){
    int r = i / C, c = i - r*C;
    out[c*R + r] = f2bu(in[i]);
  }
}

// ---- relay rows (s=0) into x buffer ----
__global__ void k_relay(const float* __restrict__ rt, u16* __restrict__ xg){
  int stride = gridDim.x * blockDim.x;
  for (int i = blockIdx.x*blockDim.x + threadIdx.x; i < NW*CC; i += stride){
    int w = i >> 8, c = i & 255;
    xg[(w*SEQ)*CC + c] = f2bu(rt[i]);
  }
}

// ---- CPE gather + BN + residual -> x rows s=1..32 (16B/lane gathers) ----
__global__ void k_cpe(const float* __restrict__ data, const u16* __restrict__ datab,
                      const int* __restrict__ neigh, const float* __restrict__ cpw,
                      const float* __restrict__ bng, const float* __restrict__ bnb,
                      const float* __restrict__ bnm, const float* __restrict__ bnv,
                      u16* __restrict__ xg){
  int n = blockIdx.x*8 + (threadIdx.x >> 5);   // 8 tokens per 256-thr block
  int l = threadIdx.x & 31;
  int c0 = l*8;
  float a[8];
  #pragma unroll
  for (int j = 0; j < 8; ++j) a[j] = 0.f;
  const int* nr = neigh + n*NKC;
  for (int k = 0; k < NKC; ++k){
    int idx = nr[k];
    s16x8 d = *(const s16x8*)(datab + idx*CC + c0);
    float4 w0 = *(const float4*)(cpw + k*CC + c0);
    float4 w1 = *(const float4*)(cpw + k*CC + c0 + 4);
    a[0] += bu2f((u16)d[0])*w0.x; a[1] += bu2f((u16)d[1])*w0.y;
    a[2] += bu2f((u16)d[2])*w0.z; a[3] += bu2f((u16)d[3])*w0.w;
    a[4] += bu2f((u16)d[4])*w1.x; a[5] += bu2f((u16)d[5])*w1.y;
    a[6] += bu2f((u16)d[6])*w1.z; a[7] += bu2f((u16)d[7])*w1.w;
  }
  s16x8 o;
  #pragma unroll
  for (int half = 0; half < 2; ++half){
    float4 dv = *(const float4*)(data + n*CC + c0 + half*4);
    float4 g  = *(const float4*)(bng + c0 + half*4);
    float4 b  = *(const float4*)(bnb + c0 + half*4);
    float4 m  = *(const float4*)(bnm + c0 + half*4);
    float4 vv = *(const float4*)(bnv + c0 + half*4);
    float x0 = dv.x + (a[half*4+0] - m.x)*rsqrtf(vv.x + 1e-5f)*g.x + b.x;
    float x1 = dv.y + (a[half*4+1] - m.y)*rsqrtf(vv.y + 1e-5f)*g.y + b.y;
    float x2 = dv.z + (a[half*4+2] - m.z)*rsqrtf(vv.z + 1e-5f)*g.z + b.z;
    float x3 = dv.w + (a[half*4+3] - m.w)*rsqrtf(vv.w + 1e-5f)*g.w + b.w;
    o[half*4+0] = (short)f2bu(x0); o[half*4+1] = (short)f2bu(x1);
    o[half*4+2] = (short)f2bu(x2); o[half*4+3] = (short)f2bu(x3);
  }
  int w = n >> 5, s = (n & 31) + 1;
  *(s16x8*)(xg + (w*SEQ + s)*CC + c0) = o;
}

// ---- fused per-window transformer block, 16 waves / window ----
// Aliasing discipline (all padded garbage is FINITE by construction):
//  A: hs (LN out; rows 33-47 zero from init, garbage-finite after P overwrite
//     — FFN only needs finite) ∪ P[8][33][72] (cols 33-47 exact zeros from
//     masked exp; cols 48-63 finite garbage but VT rows 48-63 are zero)
//  B: Q (dead after scores) ∪ och (written by PV)
//  C2: K (dead after scores) ∪ mch (FFN mid chunk)
//  VT[256][72]: cols(t) 0-47 written by qkv; 48-63 stay zero from init.
struct SharedW {
  u16 xs[33][264];                                   // 17,424 B residual
  union { u16 hs[48][264]; u16 P[8][33][72]; } A;    // 38,016 B
  union { u16 Q[48][264];  u16 och[48][264]; } B;    // 25,344 B
  union { u16 K[48][264];  u16 mch[48][264]; } C2;   // 25,344 B
  u16 VT[256][72];                                   // 36,864 B
};                                                   // 142,992 B total
static_assert(sizeof(SharedW) <= 160*1024, "LDS budget (1 block/CU)");

// (1024,1): flat-workgroup-size 1024 forces 4 waves/SIMD co-residency ->
// VGPR cap 128. Round-6's (1024,4) drove the cap to 64 and spilled
// (FETCH +169MB, WRITE +276MB of scratch traffic per dispatch).
__global__ __launch_bounds__(1024,1) void k_window(
    const u16* __restrict__ xg,
    const u16* __restrict__ qkvT, const u16* __restrict__ projT,
    const u16* __restrict__ fc1T, const u16* __restrict__ fc2T,
    const float* __restrict__ n1g, const float* __restrict__ n1b,
    const float* __restrict__ qkvb, const float* __restrict__ projb,
    const float* __restrict__ n2g, const float* __restrict__ n2b,
    const float* __restrict__ fc1b, const float* __restrict__ fc2b,
    float* __restrict__ out)
{
  __shared__ __align__(16) SharedW L;
  const int tid  = threadIdx.x;
  const int lane = tid & 63;
  const int wid  = tid >> 6;          // 0..15
  const int l15  = lane & 15;
  const int lg8  = (lane >> 4) * 8;
  const int lg4  = (lane >> 4) * 4;
  const int w    = blockIdx.x;
  const f32x4 fzero = {0.f,0.f,0.f,0.f};

  // zero everything except xs (xs fully overwritten by the load below)
  {
    f32x4* p = (f32x4*)((char*)&L + sizeof(L.xs));
    const int n16 = (int)((sizeof(SharedW) - sizeof(L.xs))/16);
    for (int i = tid; i < n16; i += 1024) p[i] = fzero;
  }
  // load x window (33 rows x 256 bf16)
  for (int ci = tid; ci < SEQ*32; ci += 1024){
    int r = ci >> 5, cp = (ci & 31) << 3;
    *(s16x8*)&L.xs[r][cp] = *(const s16x8*)(xg + (w*SEQ + r)*CC + cp);
  }
  __syncthreads();

  auto LN = [&](const float* gg, const float* bb){
    for (int r = wid; r < SEQ; r += 16){
      int c0 = lane*4;
      s16x4 xv = *(const s16x4*)&L.xs[r][c0];
      float v0 = bu2f((u16)xv[0]), v1 = bu2f((u16)xv[1]);
      float v2 = bu2f((u16)xv[2]), v3 = bu2f((u16)xv[3]);
      float s  = v0+v1+v2+v3;
      float s2 = v0*v0+v1*v1+v2*v2+v3*v3;
      #pragma unroll
      for (int msk = 1; msk < 64; msk <<= 1){
        s  += __shfl_xor(s, msk);
        s2 += __shfl_xor(s2, msk);
      }
      float mu = s * (1.f/256.f);
      float var = s2 * (1.f/256.f) - mu*mu;
      float rs = rsqrtf(var + 1e-5f);
      float4 gv = *(const float4*)(gg + c0);
      float4 bv = *(const float4*)(bb + c0);
      s16x4 o;
      o[0] = (short)f2bu((v0-mu)*rs*gv.x + bv.x);
      o[1] = (short)f2bu((v1-mu)*rs*gv.y + bv.y);
      o[2] = (short)f2bu((v2-mu)*rs*gv.z + bv.z);
      o[3] = (short)f2bu((v3-mu)*rs*gv.w + bv.w);
      *(s16x4*)&L.A.hs[r][c0] = o;
    }
  };
  LN(n1g, n1b);
  __syncthreads();

  // ===== QKV: 48x256 @ 256x768, 3 n-tiles per wave =====
  {
    #pragma unroll
    for (int i = 0; i < 3; ++i){
      int n = wid*3 + i;                 // n-tile 0..47
      int sel = n >> 4;                  // 0=q 1=k 2=v
      int cn  = (n & 15)*16 + l15;       // col within q/k/v
      int ncol = n*16 + l15;             // col within 768
      const u16* wrow = qkvT + ncol*CC + lg8;
      s16x8 bf[8];
      #pragma unroll
      for (int kk = 0; kk < 8; ++kk) bf[kk] = *(const s16x8*)(wrow + kk*32);
      float bias = qkvb[ncol];
      f32x4 acc[3] = {fzero, fzero, fzero};
      #pragma unroll
      for (int kk = 0; kk < 8; ++kk)
        #pragma unroll
        for (int m = 0; m < 3; ++m){
          s16x8 a = *(const s16x8*)&L.A.hs[m*16 + l15][kk*32 + lg8];
          acc[m] = MFMA16(a, bf[kk], acc[m]);
        }
      #pragma unroll
      for (int m = 0; m < 3; ++m)
        #pragma unroll
        for (int jj = 0; jj < 4; ++jj){
          int row = m*16 + lg4 + jj;
          float val = acc[m][jj] + bias;
          if (sel == 0)      L.B.Q[row][cn]  = f2bu(val*0.17677669529663687f); // fold attn scale
          else if (sel == 1) L.C2.K[row][cn] = f2bu(val);
          else               L.VT[cn][row]   = f2bu(val);
        }
    }
  }
  __syncthreads();

  // ===== scores + softmax: 2 waves per head (half0: m={0,2}, half1: m={1}) =====
  {
    const int h = wid & 7;
    const int half = wid >> 3;
    s16x8 bk[3];
    #pragma unroll
    for (int n = 0; n < 3; ++n) bk[n] = *(const s16x8*)&L.C2.K[n*16 + l15][h*32 + lg8];
    const int nm = half ? 1 : 2;
    for (int mi = 0; mi < nm; ++mi){
      int m = half ? 1 : (mi ? 2 : 0);
      s16x8 aq = *(const s16x8*)&L.B.Q[m*16 + l15][h*32 + lg8];
      f32x4 sc0 = MFMA16(aq, bk[0], fzero);
      f32x4 sc1 = MFMA16(aq, bk[1], fzero);
      f32x4 sc2 = MFMA16(aq, bk[2], fzero);
      #pragma unroll
      for (int jj = 0; jj < 4; ++jj){
        float a0 = sc0[jj];
        float a1 = sc1[jj];
        float a2 = (l15 == 0) ? sc2[jj] : -1e30f;   // only col 32 valid in tile n=2
        float mx = fmaxf(fmaxf(a0, a1), a2);
        #pragma unroll
        for (int msk = 1; msk < 16; msk <<= 1) mx = fmaxf(mx, __shfl_xor(mx, msk));
        float e0 = __expf(a0 - mx), e1 = __expf(a1 - mx), e2 = __expf(a2 - mx);
        float sm = e0 + e1 + e2;
        #pragma unroll
        for (int msk = 1; msk < 16; msk <<= 1) sm += __shfl_xor(sm, msk);
        float inv = 1.f / sm;
        int row = m*16 + lg4 + jj;
        if (row < SEQ){
          L.A.P[h][row][l15]      = f2bu(e0*inv);
          L.A.P[h][row][16 + l15] = f2bu(e1*inv);
          L.A.P[h][row][32 + l15] = f2bu(e2*inv);   // l15>0 writes exact zeros (cols 33-47)
        }
      }
    }
  }
  __syncthreads();   // Q dead; och (alias of Q) may now be written

  // ===== PV: 2 waves per head (n-tile = half), write och =====
  {
    const int h = wid & 7;
    const int half = wid >> 3;
    s16x8 pa0[3], pa1[3];
    #pragma unroll
    for (int m = 0; m < 3; ++m){
      int row = m*16 + l15; if (row > 32) row = 32;   // clamped: garbage rows are finite dups
      pa0[m] = *(const s16x8*)&L.A.P[h][row][lg8];
      pa1[m] = *(const s16x8*)&L.A.P[h][row][32 + lg8];
    }
    s16x8 bv0 = *(const s16x8*)&L.VT[h*32 + half*16 + l15][lg8];
    s16x8 bv1 = *(const s16x8*)&L.VT[h*32 + half*16 + l15][32 + lg8];
    int col = h*32 + half*16 + l15;
    #pragma unroll
    for (int m = 0; m < 3; ++m){
      f32x4 acc = MFMA16(pa0[m], bv0, fzero);
      acc = MFMA16(pa1[m], bv1, acc);
      #pragma unroll
      for (int jj = 0; jj < 4; ++jj)
        L.B.och[m*16 + lg4 + jj][col] = f2bu(acc[jj]);
    }
  }
  __syncthreads();

  // ===== proj (K=256 full, n-tile = wid) + residual into xs =====
  {
    int ncol = wid*16 + l15;
    const u16* wrow = projT + ncol*CC + lg8;
    s16x8 bf[8];
    #pragma unroll
    for (int kk = 0; kk < 8; ++kk) bf[kk] = *(const s16x8*)(wrow + kk*32);
    f32x4 acc[3] = {fzero, fzero, fzero};
    #pragma unroll
    for (int kk = 0; kk < 8; ++kk)
      #pragma unroll
      for (int m = 0; m < 3; ++m){
        s16x8 a = *(const s16x8*)&L.B.och[m*16 + l15][kk*32 + lg8];
        acc[m] = MFMA16(a, bf[kk], acc[m]);
      }
    float pb = projb[ncol];
    #pragma unroll
    for (int m = 0; m < 3; ++m)
      #pragma unroll
      for (int jj = 0; jj < 4; ++jj){
        int row = m*16 + lg4 + jj;
        if (row < SEQ){
          float x = bu2f(L.xs[row][ncol]) + acc[m][jj] + pb;
          L.xs[row][ncol] = f2bu(x);
        }
      }
  }
  __syncthreads();

  LN(n2g, n2b);
  __syncthreads();

  // ===== FFN: 4 chunks of 256 mid-cols; fc2 accumulated in registers =====
  f32x4 accF[3] = {fzero, fzero, fzero};

  for (int nc = 0; nc < 4; ++nc){
    // fc1: n-tile = wid within chunk, + gelu -> mch
    {
      int nl = wid*16 + l15;                // 0..255 within chunk
      int ncol = nc*256 + nl;
      const u16* wrow = fc1T + ncol*CC + lg8;
      s16x8 bf[8];
      #pragma unroll
      for (int kk = 0; kk < 8; ++kk) bf[kk] = *(const s16x8*)(wrow + kk*32);
      float bias = fc1b[ncol];
      f32x4 acc[3] = {fzero, fzero, fzero};
      #pragma unroll
      for (int kk = 0; kk < 8; ++kk)
        #pragma unroll
        for (int m = 0; m < 3; ++m){
          s16x8 a = *(const s16x8*)&L.A.hs[m*16 + l15][kk*32 + lg8];
          acc[m] = MFMA16(a, bf[kk], acc[m]);
        }
      #pragma unroll
      for (int m = 0; m < 3; ++m)
        #pragma unroll
        for (int jj = 0; jj < 4; ++jj){
          int row = m*16 + lg4 + jj;
          float xv = acc[m][jj] + bias;
          // gelu(tanh) == x * sigmoid(2z), z = 0.79788456*(x + 0.044715 x^3)
          float z2 = 1.5957691216057308f*(xv + 0.044715f*xv*xv*xv);
          float gl = xv / (1.f + __expf(-z2));
          L.C2.mch[row][nl] = f2bu(gl);
        }
    }
    __syncthreads();
    // fc2 partial accumulate (K-chunk = 256), n-tile = wid
    {
      const u16* wrow = fc2T + (wid*16 + l15)*1024 + nc*256 + lg8;
      s16x8 bf[8];
      #pragma unroll
      for (int kk = 0; kk < 8; ++kk) bf[kk] = *(const s16x8*)(wrow + kk*32);
      #pragma unroll
      for (int kk = 0; kk < 8; ++kk)
        #pragma unroll
        for (int m = 0; m < 3; ++m){
          s16x8 a = *(const s16x8*)&L.C2.mch[m*16 + l15][kk*32 + lg8];
          accF[m] = MFMA16(a, bf[kk], accF[m]);
        }
    }
    __syncthreads();
  }

  // ===== final: x + ffn, write data_out / rt =====
  {
    int col = wid*16 + l15;
    float fb = fc2b[col];
    #pragma unroll
    for (int m = 0; m < 3; ++m)
      #pragma unroll
      for (int jj = 0; jj < 4; ++jj){
        int row = m*16 + lg4 + jj;
        if (row < SEQ){
          float x = bu2f(L.xs[row][col]) + accF[m][jj] + fb;
          if (row == 0) out[NTOK*CC + w*CC + col] = x;          // relay tokens
          else          out[(w*32 + row - 1)*CC + col] = x;      // data_out
        }
      }
  }
}

extern "C" void kernel_launch(void* const* d_in, const int* in_sizes, int n_in,
                              void* d_out, int out_size, void* d_ws, size_t ws_size,
                              hipStream_t stream){
  const float* data  = (const float*)d_in[0];
  const float* relay = (const float*)d_in[1];
  const int*   neigh = (const int*)d_in[2];
  const float* cpw   = (const float*)d_in[3];
  const float* bng   = (const float*)d_in[4];
  const float* bnb   = (const float*)d_in[5];
  const float* bnm   = (const float*)d_in[6];
  const float* bnv   = (const float*)d_in[7];
  const float* n1g   = (const float*)d_in[8];
  const float* n1b   = (const float*)d_in[9];
  const float* qkvw  = (const float*)d_in[10];
  const float* qkvb  = (const float*)d_in[11];
  const float* projw = (const float*)d_in[12];
  const float* projb = (const float*)d_in[13];
  const float* n2g   = (const float*)d_in[14];
  const float* n2b   = (const float*)d_in[15];
  const float* fc1w  = (const float*)d_in[16];
  const float* fc1b  = (const float*)d_in[17];
  const float* fc2w  = (const float*)d_in[18];
  const float* fc2b  = (const float*)d_in[19];

  char* ws = (char*)d_ws;
  u16* datab = (u16*)ws;                 // 131072*256*2      = 67,108,864 B
  u16* xg    = (u16*)(ws + 67108864);    // 135168*256*2      = 69,206,016 B
  u16* qkvT  = (u16*)(ws + 136314880);   // 768*256*2         =    393,216 B
  u16* projT = (u16*)(ws + 136708096);   // 256*256*2         =    131,072 B
  u16* fc1T  = (u16*)(ws + 136839168);   // 1024*256*2        =    524,288 B
  u16* fc2T  = (u16*)(ws + 137363456);   // 256*1024*2        =    524,288 B

  k_cvt<<<4096, 256, 0, stream>>>(data, datab, NTOK*CC/4);
  k_tr<<<256, 256, 0, stream>>>(qkvw, qkvT, 256, 768);
  k_tr<<<256, 256, 0, stream>>>(projw, projT, 256, 256);
  k_tr<<<256, 256, 0, stream>>>(fc1w, fc1T, 256, 1024);
  k_tr<<<256, 256, 0, stream>>>(fc2w, fc2T, 1024, 256);
  k_relay<<<1024, 256, 0, stream>>>(relay, xg);
  k_cpe<<<NTOK/8, 256, 0, stream>>>(data, datab, neigh, cpw, bng, bnb, bnm, bnv, xg);
  k_window<<<NW, 1024, 0, stream>>>(xg, qkvT, projT, fc1T, fc2T,
                                    n1g, n1b, qkvb, projb, n2g, n2b, fc1b, fc2b,
                                    (float*)d_out);
}

// Round 11
// 1475.192 us; speedup vs baseline: 1.0670x; 1.0639x over previous
//
#include <hip/hip_runtime.h>

#define NW 4096
#define SEQ 33
#define CC 256
#define NTOK 131072
#define NKC 27

typedef unsigned short u16;
typedef __attribute__((ext_vector_type(8))) short s16x8;
typedef __attribute__((ext_vector_type(4))) short s16x4;
typedef __attribute__((ext_vector_type(4))) float f32x4;

#define MFMA16(a,b,c) __builtin_amdgcn_mfma_f32_16x16x32_bf16((a),(b),(c),0,0,0)

__device__ __forceinline__ float bu2f(u16 u){ return __uint_as_float(((unsigned int)u)<<16); }
__device__ __forceinline__ u16 f2bu(float f){
  unsigned int u = __float_as_uint(f);
  return (u16)((u + 0x7FFFu + ((u>>16)&1u)) >> 16);
}

// ---- f32 -> bf16 convert (float4 vectorized) ----
__global__ void k_cvt(const float* __restrict__ in, u16* __restrict__ out, int n4){
  int stride = gridDim.x * blockDim.x;
  for (int i = blockIdx.x*blockDim.x + threadIdx.x; i < n4; i += stride){
    float4 v = ((const float4*)in)[i];
    s16x4 o;
    o[0] = (short)f2bu(v.x); o[1] = (short)f2bu(v.y);
    o[2] = (short)f2bu(v.z); o[3] = (short)f2bu(v.w);
    ((s16x4*)out)[i] = o;
  }
}

// ---- transpose f32 (R x C) -> bf16 (C x R) ----
__global__ void k_tr(const float* __restrict__ in, u16* __restrict__ out, int R, int C){
  int stride = gridDim.x * blockDim.x;
  int total = R*C;
  for (int i = blockIdx.x*blockDim.x + threadIdx.x; i < total; i += stride){
    int r = i / C, c = i - r*C;
    out[c*R + r] = f2bu(in[i]);
  }
}

// ---- relay rows (s=0) into x buffer ----
__global__ void k_relay(const float* __restrict__ rt, u16* __restrict__ xg){
  int stride = gridDim.x * blockDim.x;
  for (int i = blockIdx.x*blockDim.x + threadIdx.x; i < NW*CC; i += stride){
    int w = i >> 8, c = i & 255;
    xg[(w*SEQ)*CC + c] = f2bu(rt[i]);
  }
}

// ---- CPE gather + BN + residual -> x rows s=1..32 (16B/lane gathers) ----
__global__ void k_cpe(const float* __restrict__ data, const u16* __restrict__ datab,
                      const int* __restrict__ neigh, const float* __restrict__ cpw,
                      const float* __restrict__ bng, const float* __restrict__ bnb,
                      const float* __restrict__ bnm, const float* __restrict__ bnv,
                      u16* __restrict__ xg){
  int n = blockIdx.x*8 + (threadIdx.x >> 5);   // 8 tokens per 256-thr block
  int l = threadIdx.x & 31;
  int c0 = l*8;
  float a[8];
  #pragma unroll
  for (int j = 0; j < 8; ++j) a[j] = 0.f;
  const int* nr = neigh + n*NKC;
  for (int k = 0; k < NKC; ++k){
    int idx = nr[k];
    s16x8 d = *(const s16x8*)(datab + idx*CC + c0);
    float4 w0 = *(const float4*)(cpw + k*CC + c0);
    float4 w1 = *(const float4*)(cpw + k*CC + c0 + 4);
    a[0] += bu2f((u16)d[0])*w0.x; a[1] += bu2f((u16)d[1])*w0.y;
    a[2] += bu2f((u16)d[2])*w0.z; a[3] += bu2f((u16)d[3])*w0.w;
    a[4] += bu2f((u16)d[4])*w1.x; a[5] += bu2f((u16)d[5])*w1.y;
    a[6] += bu2f((u16)d[6])*w1.z; a[7] += bu2f((u16)d[7])*w1.w;
  }
  s16x8 o;
  #pragma unroll
  for (int half = 0; half < 2; ++half){
    float4 dv = *(const float4*)(data + n*CC + c0 + half*4);
    float4 g  = *(const float4*)(bng + c0 + half*4);
    float4 b  = *(const float4*)(bnb + c0 + half*4);
    float4 m  = *(const float4*)(bnm + c0 + half*4);
    float4 vv = *(const float4*)(bnv + c0 + half*4);
    float x0 = dv.x + (a[half*4+0] - m.x)*rsqrtf(vv.x + 1e-5f)*g.x + b.x;
    float x1 = dv.y + (a[half*4+1] - m.y)*rsqrtf(vv.y + 1e-5f)*g.y + b.y;
    float x2 = dv.z + (a[half*4+2] - m.z)*rsqrtf(vv.z + 1e-5f)*g.z + b.z;
    float x3 = dv.w + (a[half*4+3] - m.w)*rsqrtf(vv.w + 1e-5f)*g.w + b.w;
    o[half*4+0] = (short)f2bu(x0); o[half*4+1] = (short)f2bu(x1);
    o[half*4+2] = (short)f2bu(x2); o[half*4+3] = (short)f2bu(x3);
  }
  int w = n >> 5, s = (n & 31) + 1;
  *(s16x8*)(xg + (w*SEQ + s)*CC + c0) = o;
}

// ---- fused per-window transformer block, 16 waves / window ----
// Aliasing discipline (all padded garbage is FINITE by construction):
//  A: hs (LN out; rows 33-47 zero from init) ∪ P[8][33][72] (cols 33-47 exact
//     zeros from masked exp; cols 48-63 finite garbage but VT rows 48-63 zero)
//  B: Q (dead after scores) ∪ och (written by PV)
//  C2: K (dead after scores) ∪ mch (FFN mid chunk)
//  VT[256][72]: cols(t) 0-47 written by qkv; 48-63 stay zero from init.
struct SharedW {
  u16 xs[33][264];                                   // 17,424 B residual
  union { u16 hs[48][264]; u16 P[8][33][72]; } A;    // 38,016 B
  union { u16 Q[48][264];  u16 och[48][264]; } B;    // 25,344 B
  union { u16 K[48][264];  u16 mch[48][264]; } C2;   // 25,344 B
  u16 VT[256][72];                                   // 36,864 B
};                                                   // 142,992 B total
static_assert(sizeof(SharedW) <= 160*1024, "LDS budget (1 block/CU)");

// Spill-proofing, two complementary mechanisms (round 6/7: default heuristic
// targets 8 waves/EU -> 64 VGPR cap -> ~450MB/dispatch scratch traffic):
//  (1) amdgpu_waves_per_eu(4,4): licenses 128 VGPRs (LDS already caps at 4/EU).
//  (2) B-fragment caches chunked bf[8]->2x bf[4] with #pragma unroll 1 so peak
//      per-wave demand ~55 VGPR fits even a 64 cap with zero spill.
__global__ __attribute__((amdgpu_flat_work_group_size(1024,1024), amdgpu_waves_per_eu(4,4)))
void k_window(
    const u16* __restrict__ xg,
    const u16* __restrict__ qkvT, const u16* __restrict__ projT,
    const u16* __restrict__ fc1T, const u16* __restrict__ fc2T,
    const float* __restrict__ n1g, const float* __restrict__ n1b,
    const float* __restrict__ qkvb, const float* __restrict__ projb,
    const float* __restrict__ n2g, const float* __restrict__ n2b,
    const float* __restrict__ fc1b, const float* __restrict__ fc2b,
    float* __restrict__ out)
{
  __shared__ __align__(16) SharedW L;
  const int tid  = threadIdx.x;
  const int lane = tid & 63;
  const int wid  = tid >> 6;          // 0..15
  const int l15  = lane & 15;
  const int lg8  = (lane >> 4) * 8;
  const int lg4  = (lane >> 4) * 4;
  const int w    = blockIdx.x;
  const f32x4 fzero = {0.f,0.f,0.f,0.f};

  // zero everything except xs (xs fully overwritten by the load below)
  {
    f32x4* p = (f32x4*)((char*)&L + sizeof(L.xs));
    const int n16 = (int)((sizeof(SharedW) - sizeof(L.xs))/16);
    for (int i = tid; i < n16; i += 1024) p[i] = fzero;
  }
  // load x window (33 rows x 256 bf16)
  for (int ci = tid; ci < SEQ*32; ci += 1024){
    int r = ci >> 5, cp = (ci & 31) << 3;
    *(s16x8*)&L.xs[r][cp] = *(const s16x8*)(xg + (w*SEQ + r)*CC + cp);
  }
  __syncthreads();

  auto LN = [&](const float* gg, const float* bb){
    for (int r = wid; r < SEQ; r += 16){
      int c0 = lane*4;
      s16x4 xv = *(const s16x4*)&L.xs[r][c0];
      float v0 = bu2f((u16)xv[0]), v1 = bu2f((u16)xv[1]);
      float v2 = bu2f((u16)xv[2]), v3 = bu2f((u16)xv[3]);
      float s  = v0+v1+v2+v3;
      float s2 = v0*v0+v1*v1+v2*v2+v3*v3;
      #pragma unroll
      for (int msk = 1; msk < 64; msk <<= 1){
        s  += __shfl_xor(s, msk);
        s2 += __shfl_xor(s2, msk);
      }
      float mu = s * (1.f/256.f);
      float var = s2 * (1.f/256.f) - mu*mu;
      float rs = rsqrtf(var + 1e-5f);
      float4 gv = *(const float4*)(gg + c0);
      float4 bv = *(const float4*)(bb + c0);
      s16x4 o;
      o[0] = (short)f2bu((v0-mu)*rs*gv.x + bv.x);
      o[1] = (short)f2bu((v1-mu)*rs*gv.y + bv.y);
      o[2] = (short)f2bu((v2-mu)*rs*gv.z + bv.z);
      o[3] = (short)f2bu((v3-mu)*rs*gv.w + bv.w);
      *(s16x4*)&L.A.hs[r][c0] = o;
    }
  };
  LN(n1g, n1b);
  __syncthreads();

  // ===== QKV: 48x256 @ 256x768, 3 n-tiles per wave (chunked B-cache) =====
  {
    #pragma unroll 1
    for (int i = 0; i < 3; ++i){
      int n = wid*3 + i;                 // n-tile 0..47
      int sel = n >> 4;                  // 0=q 1=k 2=v
      int cn  = (n & 15)*16 + l15;       // col within q/k/v
      int ncol = n*16 + l15;             // col within 768
      const u16* wrow = qkvT + ncol*CC + lg8;
      float bias = qkvb[ncol];
      f32x4 acc[3] = {fzero, fzero, fzero};
      #pragma unroll 1
      for (int kc = 0; kc < 2; ++kc){
        s16x8 bf[4];
        #pragma unroll
        for (int kk = 0; kk < 4; ++kk) bf[kk] = *(const s16x8*)(wrow + (kc*4 + kk)*32);
        #pragma unroll
        for (int kk = 0; kk < 4; ++kk)
          #pragma unroll
          for (int m = 0; m < 3; ++m){
            s16x8 a = *(const s16x8*)&L.A.hs[m*16 + l15][(kc*4 + kk)*32 + lg8];
            acc[m] = MFMA16(a, bf[kk], acc[m]);
          }
      }
      #pragma unroll
      for (int m = 0; m < 3; ++m)
        #pragma unroll
        for (int jj = 0; jj < 4; ++jj){
          int row = m*16 + lg4 + jj;
          float val = acc[m][jj] + bias;
          if (sel == 0)      L.B.Q[row][cn]  = f2bu(val*0.17677669529663687f); // fold attn scale
          else if (sel == 1) L.C2.K[row][cn] = f2bu(val);
          else               L.VT[cn][row]   = f2bu(val);
        }
    }
  }
  __syncthreads();

  // ===== scores + softmax: 2 waves per head (half0: m={0,2}, half1: m={1}) =====
  {
    const int h = wid & 7;
    const int half = wid >> 3;
    s16x8 bk[3];
    #pragma unroll
    for (int n = 0; n < 3; ++n) bk[n] = *(const s16x8*)&L.C2.K[n*16 + l15][h*32 + lg8];
    const int nm = half ? 1 : 2;
    for (int mi = 0; mi < nm; ++mi){
      int m = half ? 1 : (mi ? 2 : 0);
      s16x8 aq = *(const s16x8*)&L.B.Q[m*16 + l15][h*32 + lg8];
      f32x4 sc0 = MFMA16(aq, bk[0], fzero);
      f32x4 sc1 = MFMA16(aq, bk[1], fzero);
      f32x4 sc2 = MFMA16(aq, bk[2], fzero);
      #pragma unroll
      for (int jj = 0; jj < 4; ++jj){
        float a0 = sc0[jj];
        float a1 = sc1[jj];
        float a2 = (l15 == 0) ? sc2[jj] : -1e30f;   // only col 32 valid in tile n=2
        float mx = fmaxf(fmaxf(a0, a1), a2);
        #pragma unroll
        for (int msk = 1; msk < 16; msk <<= 1) mx = fmaxf(mx, __shfl_xor(mx, msk));
        float e0 = __expf(a0 - mx), e1 = __expf(a1 - mx), e2 = __expf(a2 - mx);
        float sm = e0 + e1 + e2;
        #pragma unroll
        for (int msk = 1; msk < 16; msk <<= 1) sm += __shfl_xor(sm, msk);
        float inv = 1.f / sm;
        int row = m*16 + lg4 + jj;
        if (row < SEQ){
          L.A.P[h][row][l15]      = f2bu(e0*inv);
          L.A.P[h][row][16 + l15] = f2bu(e1*inv);
          L.A.P[h][row][32 + l15] = f2bu(e2*inv);   // l15>0 writes exact zeros (cols 33-47)
        }
      }
    }
  }
  __syncthreads();   // Q dead; och (alias of Q) may now be written

  // ===== PV: 2 waves per head (n-tile = half), write och =====
  {
    const int h = wid & 7;
    const int half = wid >> 3;
    s16x8 bv0 = *(const s16x8*)&L.VT[h*32 + half*16 + l15][lg8];
    s16x8 bv1 = *(const s16x8*)&L.VT[h*32 + half*16 + l15][32 + lg8];
    int col = h*32 + half*16 + l15;
    #pragma unroll
    for (int m = 0; m < 3; ++m){
      int row = m*16 + l15; if (row > 32) row = 32;   // clamped: garbage rows are finite dups
      s16x8 pa0 = *(const s16x8*)&L.A.P[h][row][lg8];
      s16x8 pa1 = *(const s16x8*)&L.A.P[h][row][32 + lg8];
      f32x4 acc = MFMA16(pa0, bv0, fzero);
      acc = MFMA16(pa1, bv1, acc);
      #pragma unroll
      for (int jj = 0; jj < 4; ++jj)
        L.B.och[m*16 + lg4 + jj][col] = f2bu(acc[jj]);
    }
  }
  __syncthreads();

  // ===== proj (K=256 full, n-tile = wid) + residual into xs (chunked) =====
  {
    int ncol = wid*16 + l15;
    const u16* wrow = projT + ncol*CC + lg8;
    f32x4 acc[3] = {fzero, fzero, fzero};
    #pragma unroll 1
    for (int kc = 0; kc < 2; ++kc){
      s16x8 bf[4];
      #pragma unroll
      for (int kk = 0; kk < 4; ++kk) bf[kk] = *(const s16x8*)(wrow + (kc*4 + kk)*32);
      #pragma unroll
      for (int kk = 0; kk < 4; ++kk)
        #pragma unroll
        for (int m = 0; m < 3; ++m){
          s16x8 a = *(const s16x8*)&L.B.och[m*16 + l15][(kc*4 + kk)*32 + lg8];
          acc[m] = MFMA16(a, bf[kk], acc[m]);
        }
    }
    float pb = projb[ncol];
    #pragma unroll
    for (int m = 0; m < 3; ++m)
      #pragma unroll
      for (int jj = 0; jj < 4; ++jj){
        int row = m*16 + lg4 + jj;
        if (row < SEQ){
          float x = bu2f(L.xs[row][ncol]) + acc[m][jj] + pb;
          L.xs[row][ncol] = f2bu(x);
        }
      }
  }
  __syncthreads();

  LN(n2g, n2b);
  __syncthreads();

  // ===== FFN: 4 chunks of 256 mid-cols; fc2 accumulated in registers =====
  f32x4 accF[3] = {fzero, fzero, fzero};

  #pragma unroll 1
  for (int nc = 0; nc < 4; ++nc){
    // fc1: n-tile = wid within chunk, + gelu -> mch (chunked B-cache)
    {
      int nl = wid*16 + l15;                // 0..255 within chunk
      int ncol = nc*256 + nl;
      const u16* wrow = fc1T + ncol*CC + lg8;
      float bias = fc1b[ncol];
      f32x4 acc[3] = {fzero, fzero, fzero};
      #pragma unroll 1
      for (int kc = 0; kc < 2; ++kc){
        s16x8 bf[4];
        #pragma unroll
        for (int kk = 0; kk < 4; ++kk) bf[kk] = *(const s16x8*)(wrow + (kc*4 + kk)*32);
        #pragma unroll
        for (int kk = 0; kk < 4; ++kk)
          #pragma unroll
          for (int m = 0; m < 3; ++m){
            s16x8 a = *(const s16x8*)&L.A.hs[m*16 + l15][(kc*4 + kk)*32 + lg8];
            acc[m] = MFMA16(a, bf[kk], acc[m]);
          }
      }
      #pragma unroll
      for (int m = 0; m < 3; ++m)
        #pragma unroll
        for (int jj = 0; jj < 4; ++jj){
          int row = m*16 + lg4 + jj;
          float xv = acc[m][jj] + bias;
          // gelu(tanh) == x * sigmoid(2z), z = 0.79788456*(x + 0.044715 x^3)
          float z2 = 1.5957691216057308f*(xv + 0.044715f*xv*xv*xv);
          float gl = xv / (1.f + __expf(-z2));
          L.C2.mch[row][nl] = f2bu(gl);
        }
    }
    __syncthreads();
    // fc2 partial accumulate (K-chunk = 256), n-tile = wid (chunked B-cache)
    {
      const u16* wrow = fc2T + (wid*16 + l15)*1024 + nc*256 + lg8;
      #pragma unroll 1
      for (int kc = 0; kc < 2; ++kc){
        s16x8 bf[4];
        #pragma unroll
        for (int kk = 0; kk < 4; ++kk) bf[kk] = *(const s16x8*)(wrow + (kc*4 + kk)*32);
        #pragma unroll
        for (int kk = 0; kk < 4; ++kk)
          #pragma unroll
          for (int m = 0; m < 3; ++m){
            s16x8 a = *(const s16x8*)&L.C2.mch[m*16 + l15][(kc*4 + kk)*32 + lg8];
            accF[m] = MFMA16(a, bf[kk], accF[m]);
          }
      }
    }
    __syncthreads();
  }

  // ===== final: x + ffn, write data_out / rt =====
  {
    int col = wid*16 + l15;
    float fb = fc2b[col];
    #pragma unroll
    for (int m = 0; m < 3; ++m)
      #pragma unroll
      for (int jj = 0; jj < 4; ++jj){
        int row = m*16 + lg4 + jj;
        if (row < SEQ){
          float x = bu2f(L.xs[row][col]) + accF[m][jj] + fb;
          if (row == 0) out[NTOK*CC + w*CC + col] = x;          // relay tokens
          else          out[(w*32 + row - 1)*CC + col] = x;      // data_out
        }
      }
  }
}

extern "C" void kernel_launch(void* const* d_in, const int* in_sizes, int n_in,
                              void* d_out, int out_size, void* d_ws, size_t ws_size,
                              hipStream_t stream){
  const float* data  = (const float*)d_in[0];
  const float* relay = (const float*)d_in[1];
  const int*   neigh = (const int*)d_in[2];
  const float* cpw   = (const float*)d_in[3];
  const float* bng   = (const float*)d_in[4];
  const float* bnb   = (const float*)d_in[5];
  const float* bnm   = (const float*)d_in[6];
  const float* bnv   = (const float*)d_in[7];
  const float* n1g   = (const float*)d_in[8];
  const float* n1b   = (const float*)d_in[9];
  const float* qkvw  = (const float*)d_in[10];
  const float* qkvb  = (const float*)d_in[11];
  const float* projw = (const float*)d_in[12];
  const float* projb = (const float*)d_in[13];
  const float* n2g   = (const float*)d_in[14];
  const float* n2b   = (const float*)d_in[15];
  const float* fc1w  = (const float*)d_in[16];
  const float* fc1b  = (const float*)d_in[17];
  const float* fc2w  = (const float*)d_in[18];
  const float* fc2b  = (const float*)d_in[19];

  char* ws = (char*)d_ws;
  u16* datab = (u16*)ws;                 // 131072*256*2      = 67,108,864 B
  u16* xg    = (u16*)(ws + 67108864);    // 135168*256*2      = 69,206,016 B
  u16* qkvT  = (u16*)(ws + 136314880);   // 768*256*2         =    393,216 B
  u16* projT = (u16*)(ws + 136708096);   // 256*256*2         =    131,072 B
  u16* fc1T  = (u16*)(ws + 136839168);   // 1024*256*2        =    524,288 B
  u16* fc2T  = (u16*)(ws + 137363456);   // 256*1024*2        =    524,288 B

  k_cvt<<<4096, 256, 0, stream>>>(data, datab, NTOK*CC/4);
  k_tr<<<256, 256, 0, stream>>>(qkvw, qkvT, 256, 768);
  k_tr<<<256, 256, 0, stream>>>(projw, projT, 256, 256);
  k_tr<<<256, 256, 0, stream>>>(fc1w, fc1T, 256, 1024);
  k_tr<<<256, 256, 0, stream>>>(fc2w, fc2T, 1024, 256);
  k_relay<<<1024, 256, 0, stream>>>(relay, xg);
  k_cpe<<<NTOK/8, 256, 0, stream>>>(data, datab, neigh, cpw, bng, bnb, bnm, bnv, xg);
  k_window<<<NW, 1024, 0, stream>>>(xg, qkvT, projT, fc1T, fc2T,
                                    n1g, n1b, qkvb, projb, n2g, n2b, fc1b, fc2b,
                                    (float*)d_out);
}

// Round 12
// 1435.394 us; speedup vs baseline: 1.0966x; 1.0277x over previous
//
#include <hip/hip_runtime.h>

#define NW 4096
#define SEQ 33
#define CC 256
#define NTOK 131072
#define NKC 27

typedef unsigned short u16;
typedef __attribute__((ext_vector_type(8))) short s16x8;
typedef __attribute__((ext_vector_type(4))) short s16x4;
typedef __attribute__((ext_vector_type(4))) float f32x4;

#define MFMA16(a,b,c) __builtin_amdgcn_mfma_f32_16x16x32_bf16((a),(b),(c),0,0,0)

__device__ __forceinline__ float bu2f(u16 u){ return __uint_as_float(((unsigned int)u)<<16); }
__device__ __forceinline__ u16 f2bu(float f){
  unsigned int u = __float_as_uint(f);
  return (u16)((u + 0x7FFFu + ((u>>16)&1u)) >> 16);
}

// ---- f32 -> bf16 convert (float4 vectorized) ----
__global__ void k_cvt(const float* __restrict__ in, u16* __restrict__ out, int n4){
  int stride = gridDim.x * blockDim.x;
  for (int i = blockIdx.x*blockDim.x + threadIdx.x; i < n4; i += stride){
    float4 v = ((const float4*)in)[i];
    s16x4 o;
    o[0] = (short)f2bu(v.x); o[1] = (short)f2bu(v.y);
    o[2] = (short)f2bu(v.z); o[3] = (short)f2bu(v.w);
    ((s16x4*)out)[i] = o;
  }
}

// ---- transpose f32 (R x C) -> bf16 (C x R) ----
__global__ void k_tr(const float* __restrict__ in, u16* __restrict__ out, int R, int C){
  int stride = gridDim.x * blockDim.x;
  int total = R*C;
  for (int i = blockIdx.x*blockDim.x + threadIdx.x; i < total; i += stride){
    int r = i / C, c = i - r*C;
    out[c*R + r] = f2bu(in[i]);
  }
}

// ---- relay rows (s=0) into x buffer ----
__global__ void k_relay(const float* __restrict__ rt, u16* __restrict__ xg){
  int stride = gridDim.x * blockDim.x;
  for (int i = blockIdx.x*blockDim.x + threadIdx.x; i < NW*CC; i += stride){
    int w = i >> 8, c = i & 255;
    xg[(w*SEQ)*CC + c] = f2bu(rt[i]);
  }
}

// ---- CPE gather + BN + residual -> x rows s=1..32 (16B/lane gathers) ----
__global__ void k_cpe(const float* __restrict__ data, const u16* __restrict__ datab,
                      const int* __restrict__ neigh, const float* __restrict__ cpw,
                      const float* __restrict__ bng, const float* __restrict__ bnb,
                      const float* __restrict__ bnm, const float* __restrict__ bnv,
                      u16* __restrict__ xg){
  int n = blockIdx.x*8 + (threadIdx.x >> 5);   // 8 tokens per 256-thr block
  int l = threadIdx.x & 31;
  int c0 = l*8;
  float a[8];
  #pragma unroll
  for (int j = 0; j < 8; ++j) a[j] = 0.f;
  const int* nr = neigh + n*NKC;
  for (int k = 0; k < NKC; ++k){
    int idx = nr[k];
    s16x8 d = *(const s16x8*)(datab + idx*CC + c0);
    float4 w0 = *(const float4*)(cpw + k*CC + c0);
    float4 w1 = *(const float4*)(cpw + k*CC + c0 + 4);
    a[0] += bu2f((u16)d[0])*w0.x; a[1] += bu2f((u16)d[1])*w0.y;
    a[2] += bu2f((u16)d[2])*w0.z; a[3] += bu2f((u16)d[3])*w0.w;
    a[4] += bu2f((u16)d[4])*w1.x; a[5] += bu2f((u16)d[5])*w1.y;
    a[6] += bu2f((u16)d[6])*w1.z; a[7] += bu2f((u16)d[7])*w1.w;
  }
  s16x8 o;
  #pragma unroll
  for (int half = 0; half < 2; ++half){
    float4 dv = *(const float4*)(data + n*CC + c0 + half*4);
    float4 g  = *(const float4*)(bng + c0 + half*4);
    float4 b  = *(const float4*)(bnb + c0 + half*4);
    float4 m  = *(const float4*)(bnm + c0 + half*4);
    float4 vv = *(const float4*)(bnv + c0 + half*4);
    float x0 = dv.x + (a[half*4+0] - m.x)*rsqrtf(vv.x + 1e-5f)*g.x + b.x;
    float x1 = dv.y + (a[half*4+1] - m.y)*rsqrtf(vv.y + 1e-5f)*g.y + b.y;
    float x2 = dv.z + (a[half*4+2] - m.z)*rsqrtf(vv.z + 1e-5f)*g.z + b.z;
    float x3 = dv.w + (a[half*4+3] - m.w)*rsqrtf(vv.w + 1e-5f)*g.w + b.w;
    o[half*4+0] = (short)f2bu(x0); o[half*4+1] = (short)f2bu(x1);
    o[half*4+2] = (short)f2bu(x2); o[half*4+3] = (short)f2bu(x3);
  }
  int w = n >> 5, s = (n & 31) + 1;
  *(s16x8*)(xg + (w*SEQ + s)*CC + c0) = o;
}

// ---- fused per-window transformer block, 16 waves, 10 barriers ----
// Row-clamp trick: MFMA output row i depends only on A-row i, so padded A-rows
// >32 read row 32 (uniform -> LDS broadcast) and all output writes are masked
// row<SEQ. Q/K/och/mch/hs therefore hold only 33 rows.
// Aliasing audit (barrier numbers in parentheses):
//  A: hs (LN1 out, dead after QKV(3); LN2 rewrites after (6)) ∪ P[8][33][72]
//     (written in merged attn phase (3..4); each wave reads only rows it wrote;
//     P cols 33-47 explicit zeros, cols 48-63 zero-init; dead after (4))
//  C2: K (dead after (4)) ∪ mch0 (written FC1(0) after (6))
//  D:  och (written (3..4), read proj, dead after (5)) ∪ mch1 (written FC1(1) after (7))
//  VT[256][72]: rows(t) 0-32 written in QKV (masked); t 33-71 stay zero-init.
struct SharedW {
  u16 xs[33][264];                                     // 17,424 residual
  union { u16 hs[33][264]; u16 P[8][33][72]; } A;      // 38,016 (P dominates)
  u16 Q[33][264];                                      // 17,424
  union { u16 K[33][264];   u16 mch0[33][264]; } C2;   // 17,424
  union { u16 och[33][264]; u16 mch1[33][264]; } D;    // 17,424
  u16 VT[256][72];                                     // 36,864
};                                                     // 144,576 total
static_assert(sizeof(SharedW) <= 160*1024, "LDS budget (1 block/CU)");

__global__ __attribute__((amdgpu_flat_work_group_size(1024,1024), amdgpu_waves_per_eu(4,4)))
void k_window(
    const u16* __restrict__ xg,
    const u16* __restrict__ qkvT, const u16* __restrict__ projT,
    const u16* __restrict__ fc1T, const u16* __restrict__ fc2T,
    const float* __restrict__ n1g, const float* __restrict__ n1b,
    const float* __restrict__ qkvb, const float* __restrict__ projb,
    const float* __restrict__ n2g, const float* __restrict__ n2b,
    const float* __restrict__ fc1b, const float* __restrict__ fc2b,
    float* __restrict__ out)
{
  __shared__ __align__(16) SharedW L;
  const int tid  = threadIdx.x;
  const int lane = tid & 63;
  const int wid  = tid >> 6;          // 0..15
  const int l15  = lane & 15;
  const int lg8  = (lane >> 4) * 8;
  const int lg4  = (lane >> 4) * 4;
  const int w    = blockIdx.x;
  const f32x4 fzero = {0.f,0.f,0.f,0.f};

  // zero everything except xs (needed: P cols 48-63, VT rows 33-71)
  {
    f32x4* p = (f32x4*)((char*)&L + sizeof(L.xs));
    const int n16 = (int)((sizeof(SharedW) - sizeof(L.xs))/16);
    for (int i = tid; i < n16; i += 1024) p[i] = fzero;
  }
  // load x window (33 rows x 256 bf16)
  for (int ci = tid; ci < SEQ*32; ci += 1024){
    int r = ci >> 5, cp = (ci & 31) << 3;
    *(s16x8*)&L.xs[r][cp] = *(const s16x8*)(xg + (w*SEQ + r)*CC + cp);
  }
  __syncthreads();                                            // (1)

  auto LN = [&](const float* gg, const float* bb){
    for (int r = wid; r < SEQ; r += 16){
      int c0 = lane*4;
      s16x4 xv = *(const s16x4*)&L.xs[r][c0];
      float v0 = bu2f((u16)xv[0]), v1 = bu2f((u16)xv[1]);
      float v2 = bu2f((u16)xv[2]), v3 = bu2f((u16)xv[3]);
      float s  = v0+v1+v2+v3;
      float s2 = v0*v0+v1*v1+v2*v2+v3*v3;
      #pragma unroll
      for (int msk = 1; msk < 64; msk <<= 1){
        s  += __shfl_xor(s, msk);
        s2 += __shfl_xor(s2, msk);
      }
      float mu = s * (1.f/256.f);
      float var = s2 * (1.f/256.f) - mu*mu;
      float rs = rsqrtf(var + 1e-5f);
      float4 gv = *(const float4*)(gg + c0);
      float4 bv = *(const float4*)(bb + c0);
      s16x4 o;
      o[0] = (short)f2bu((v0-mu)*rs*gv.x + bv.x);
      o[1] = (short)f2bu((v1-mu)*rs*gv.y + bv.y);
      o[2] = (short)f2bu((v2-mu)*rs*gv.z + bv.z);
      o[3] = (short)f2bu((v3-mu)*rs*gv.w + bv.w);
      *(s16x4*)&L.A.hs[r][c0] = o;
    }
  };
  LN(n1g, n1b);
  __syncthreads();                                            // (2)

  // ===== QKV: 48x256 @ 256x768, 3 n-tiles/wave (chunked B, clamped A) =====
  {
    #pragma unroll 1
    for (int i = 0; i < 3; ++i){
      int n = wid*3 + i;                 // n-tile 0..47
      int sel = n >> 4;                  // 0=q 1=k 2=v
      int cn  = (n & 15)*16 + l15;       // col within q/k/v
      int ncol = n*16 + l15;             // col within 768
      const u16* wrow = qkvT + ncol*CC + lg8;
      float bias = qkvb[ncol];
      f32x4 acc[3] = {fzero, fzero, fzero};
      #pragma unroll 1
      for (int kc = 0; kc < 2; ++kc){
        s16x8 bf[4];
        #pragma unroll
        for (int kk = 0; kk < 4; ++kk) bf[kk] = *(const s16x8*)(wrow + (kc*4 + kk)*32);
        #pragma unroll
        for (int kk = 0; kk < 4; ++kk)
          #pragma unroll
          for (int m = 0; m < 3; ++m){
            int ar = (m == 2) ? 32 : (m*16 + l15);            // clamp (row-dup, masked out)
            s16x8 a = *(const s16x8*)&L.A.hs[ar][(kc*4 + kk)*32 + lg8];
            acc[m] = MFMA16(a, bf[kk], acc[m]);
          }
      }
      #pragma unroll
      for (int m = 0; m < 3; ++m)
        #pragma unroll
        for (int jj = 0; jj < 4; ++jj){
          int row = m*16 + lg4 + jj;
          if (row < SEQ){
            float val = acc[m][jj] + bias;
            if (sel == 0)      L.Q[row][cn]    = f2bu(val*0.17677669529663687f); // fold attn scale
            else if (sel == 1) L.C2.K[row][cn] = f2bu(val);
            else               L.VT[cn][row]   = f2bu(val);
          }
        }
    }
  }
  __syncthreads();                                            // (3)

  // ===== merged scores + softmax + PV (per-wave by q-rows; no inner barrier)
  // half0: m={0,2}, half1: m={1}; each wave reads only P rows it wrote.
  {
    const int h = wid & 7;
    const int half = wid >> 3;
    s16x8 bk0 = *(const s16x8*)&L.C2.K[l15][h*32 + lg8];
    s16x8 bk1 = *(const s16x8*)&L.C2.K[16 + l15][h*32 + lg8];
    s16x8 bk2 = *(const s16x8*)&L.C2.K[32][h*32 + lg8];       // uniform row -> broadcast
    const int nm = half ? 1 : 2;
    for (int mi = 0; mi < nm; ++mi){
      int m = half ? 1 : (mi ? 2 : 0);
      int ar = (m == 2) ? 32 : (m*16 + l15);
      s16x8 aq = *(const s16x8*)&L.Q[ar][h*32 + lg8];
      f32x4 sc0 = MFMA16(aq, bk0, fzero);
      f32x4 sc1 = MFMA16(aq, bk1, fzero);
      f32x4 sc2 = MFMA16(aq, bk2, fzero);
      #pragma unroll
      for (int jj = 0; jj < 4; ++jj){
        float a0 = sc0[jj];
        float a1 = sc1[jj];
        float a2 = (l15 == 0) ? sc2[jj] : -1e30f;   // only col 32 valid in tile n=2
        float mx = fmaxf(fmaxf(a0, a1), a2);
        #pragma unroll
        for (int msk = 1; msk < 16; msk <<= 1) mx = fmaxf(mx, __shfl_xor(mx, msk));
        float e0 = __expf(a0 - mx), e1 = __expf(a1 - mx), e2 = __expf(a2 - mx);
        float sm = e0 + e1 + e2;
        #pragma unroll
        for (int msk = 1; msk < 16; msk <<= 1) sm += __shfl_xor(sm, msk);
        float inv = 1.f / sm;
        int row = m*16 + lg4 + jj;
        if (row < SEQ){
          L.A.P[h][row][l15]      = f2bu(e0*inv);
          L.A.P[h][row][16 + l15] = f2bu(e1*inv);
          L.A.P[h][row][32 + l15] = f2bu(e2*inv);   // l15>0 writes exact zeros (cols 33-47)
        }
      }
    }
    // PV for this wave's own q-rows (both d-tiles); P deps are same-wave (lgkmcnt)
    s16x8 bva[2], bvb[2];
    #pragma unroll
    for (int nd = 0; nd < 2; ++nd){
      bva[nd] = *(const s16x8*)&L.VT[h*32 + nd*16 + l15][lg8];
      bvb[nd] = *(const s16x8*)&L.VT[h*32 + nd*16 + l15][32 + lg8];
    }
    for (int mi = 0; mi < nm; ++mi){
      int m = half ? 1 : (mi ? 2 : 0);
      int pr = (m == 2) ? 32 : (m*16 + l15);
      s16x8 pa0 = *(const s16x8*)&L.A.P[h][pr][lg8];
      s16x8 pa1 = *(const s16x8*)&L.A.P[h][pr][32 + lg8];
      #pragma unroll
      for (int nd = 0; nd < 2; ++nd){
        f32x4 acc = MFMA16(pa0, bva[nd], fzero);
        acc = MFMA16(pa1, bvb[nd], acc);
        #pragma unroll
        for (int jj = 0; jj < 4; ++jj){
          int row = m*16 + lg4 + jj;
          if (row < SEQ)
            L.D.och[row][h*32 + nd*16 + l15] = f2bu(acc[jj]);
        }
      }
    }
  }
  __syncthreads();                                            // (4)

  // ===== proj (K=256 full, n-tile = wid) + residual into xs (chunked) =====
  {
    int ncol = wid*16 + l15;
    const u16* wrow = projT + ncol*CC + lg8;
    f32x4 acc[3] = {fzero, fzero, fzero};
    #pragma unroll 1
    for (int kc = 0; kc < 2; ++kc){
      s16x8 bf[4];
      #pragma unroll
      for (int kk = 0; kk < 4; ++kk) bf[kk] = *(const s16x8*)(wrow + (kc*4 + kk)*32);
      #pragma unroll
      for (int kk = 0; kk < 4; ++kk)
        #pragma unroll
        for (int m = 0; m < 3; ++m){
          int ar = (m == 2) ? 32 : (m*16 + l15);
          s16x8 a = *(const s16x8*)&L.D.och[ar][(kc*4 + kk)*32 + lg8];
          acc[m] = MFMA16(a, bf[kk], acc[m]);
        }
    }
    float pb = projb[ncol];
    #pragma unroll
    for (int m = 0; m < 3; ++m)
      #pragma unroll
      for (int jj = 0; jj < 4; ++jj){
        int row = m*16 + lg4 + jj;
        if (row < SEQ){
          float x = bu2f(L.xs[row][ncol]) + acc[m][jj] + pb;
          L.xs[row][ncol] = f2bu(x);
        }
      }
  }
  __syncthreads();                                            // (5)

  LN(n2g, n2b);
  __syncthreads();                                            // (6)

  // ===== FFN: 4 chunks of 256 mid-cols, double-buffered mch =====
  f32x4 accF[3] = {fzero, fzero, fzero};

  auto FC1 = [&](int nc, u16 (*mch)[264]){
    int nl = wid*16 + l15;                // 0..255 within chunk
    int ncol = nc*256 + nl;
    const u16* wrow = fc1T + ncol*CC + lg8;
    float bias = fc1b[ncol];
    f32x4 acc[3] = {fzero, fzero, fzero};
    #pragma unroll 1
    for (int kc = 0; kc < 2; ++kc){
      s16x8 bf[4];
      #pragma unroll
      for (int kk = 0; kk < 4; ++kk) bf[kk] = *(const s16x8*)(wrow + (kc*4 + kk)*32);
      #pragma unroll
      for (int kk = 0; kk < 4; ++kk)
        #pragma unroll
        for (int m = 0; m < 3; ++m){
          int ar = (m == 2) ? 32 : (m*16 + l15);
          s16x8 a = *(const s16x8*)&L.A.hs[ar][(kc*4 + kk)*32 + lg8];
          acc[m] = MFMA16(a, bf[kk], acc[m]);
        }
    }
    #pragma unroll
    for (int m = 0; m < 3; ++m)
      #pragma unroll
      for (int jj = 0; jj < 4; ++jj){
        int row = m*16 + lg4 + jj;
        if (row < SEQ){
          float xv = acc[m][jj] + bias;
          // gelu(tanh) == x * sigmoid(2z), z = 0.79788456*(x + 0.044715 x^3)
          float z2 = 1.5957691216057308f*(xv + 0.044715f*xv*xv*xv);
          float gl = xv / (1.f + __expf(-z2));
          mch[row][nl] = f2bu(gl);
        }
      }
  };
  auto FC2 = [&](int nc, const u16 (*mch)[264]){
    const u16* wrow = fc2T + (wid*16 + l15)*1024 + nc*256 + lg8;
    #pragma unroll 1
    for (int kc = 0; kc < 2; ++kc){
      s16x8 bf[4];
      #pragma unroll
      for (int kk = 0; kk < 4; ++kk) bf[kk] = *(const s16x8*)(wrow + (kc*4 + kk)*32);
      #pragma unroll
      for (int kk = 0; kk < 4; ++kk)
        #pragma unroll
        for (int m = 0; m < 3; ++m){
          int ar = (m == 2) ? 32 : (m*16 + l15);
          s16x8 a = *(const s16x8*)&mch[ar][(kc*4 + kk)*32 + lg8];
          accF[m] = MFMA16(a, bf[kk], accF[m]);
        }
    }
  };

  FC1(0, L.C2.mch0);
  __syncthreads();                                            // (7)
  FC2(0, L.C2.mch0); FC1(1, L.D.mch1);
  __syncthreads();                                            // (8)
  FC2(1, L.D.mch1);  FC1(2, L.C2.mch0);
  __syncthreads();                                            // (9)
  FC2(2, L.C2.mch0); FC1(3, L.D.mch1);
  __syncthreads();                                            // (10)
  FC2(3, L.D.mch1);

  // ===== final: x + ffn, write data_out / rt (register epilogue, no barrier)
  {
    int col = wid*16 + l15;
    float fb = fc2b[col];
    #pragma unroll
    for (int m = 0; m < 3; ++m)
      #pragma unroll
      for (int jj = 0; jj < 4; ++jj){
        int row = m*16 + lg4 + jj;
        if (row < SEQ){
          float x = bu2f(L.xs[row][col]) + accF[m][jj] + fb;
          if (row == 0) out[NTOK*CC + w*CC + col] = x;          // relay tokens
          else          out[(w*32 + row - 1)*CC + col] = x;      // data_out
        }
      }
  }
}

extern "C" void kernel_launch(void* const* d_in, const int* in_sizes, int n_in,
                              void* d_out, int out_size, void* d_ws, size_t ws_size,
                              hipStream_t stream){
  const float* data  = (const float*)d_in[0];
  const float* relay = (const float*)d_in[1];
  const int*   neigh = (const int*)d_in[2];
  const float* cpw   = (const float*)d_in[3];
  const float* bng   = (const float*)d_in[4];
  const float* bnb   = (const float*)d_in[5];
  const float* bnm   = (const float*)d_in[6];
  const float* bnv   = (const float*)d_in[7];
  const float* n1g   = (const float*)d_in[8];
  const float* n1b   = (const float*)d_in[9];
  const float* qkvw  = (const float*)d_in[10];
  const float* qkvb  = (const float*)d_in[11];
  const float* projw = (const float*)d_in[12];
  const float* projb = (const float*)d_in[13];
  const float* n2g   = (const float*)d_in[14];
  const float* n2b   = (const float*)d_in[15];
  const float* fc1w  = (const float*)d_in[16];
  const float* fc1b  = (const float*)d_in[17];
  const float* fc2w  = (const float*)d_in[18];
  const float* fc2b  = (const float*)d_in[19];

  char* ws = (char*)d_ws;
  u16* datab = (u16*)ws;                 // 131072*256*2      = 67,108,864 B
  u16* xg    = (u16*)(ws + 67108864);    // 135168*256*2      = 69,206,016 B
  u16* qkvT  = (u16*)(ws + 136314880);   // 768*256*2         =    393,216 B
  u16* projT = (u16*)(ws + 136708096);   // 256*256*2         =    131,072 B
  u16* fc1T  = (u16*)(ws + 136839168);   // 1024*256*2        =    524,288 B
  u16* fc2T  = (u16*)(ws + 137363456);   // 256*1024*2        =    524,288 B

  k_cvt<<<4096, 256, 0, stream>>>(data, datab, NTOK*CC/4);
  k_tr<<<256, 256, 0, stream>>>(qkvw, qkvT, 256, 768);
  k_tr<<<256, 256, 0, stream>>>(projw, projT, 256, 256);
  k_tr<<<256, 256, 0, stream>>>(fc1w, fc1T, 256, 1024);
  k_tr<<<256, 256, 0, stream>>>(fc2w, fc2T, 1024, 256);
  k_relay<<<1024, 256, 0, stream>>>(relay, xg);
  k_cpe<<<NTOK/8, 256, 0, stream>>>(data, datab, neigh, cpw, bng, bnb, bnm, bnv, xg);
  k_window<<<NW, 1024, 0, stream>>>(xg, qkvT, projT, fc1T, fc2T,
                                    n1g, n1b, qkvb, projb, n2g, n2b, fc1b, fc2b,
                                    (float*)d_out);
}